// Round 7
// baseline (96.879 us; speedup 1.0000x reference)
//
#include <hip/hip_runtime.h>
#include <hip/hip_bf16.h>

typedef short v8s __attribute__((ext_vector_type(8)));
typedef float v4f __attribute__((ext_vector_type(4)));

#define NC 32
#define NT 1024
#define NU 32
#define NH 128

// Native RNE f32->bf16 (compiler lowers to v_cvt_pk_bf16_f32).
static __device__ __forceinline__ unsigned short f2bf(float f) {
    union { __hip_bfloat16 h; unsigned short s; } u;
    u.h = __float2bfloat16(f);
    return u.s;
}
static __device__ __forceinline__ unsigned int f2bf2(float lo, float hi) {
    union { __hip_bfloat162 h2; unsigned int s; } u;
    u.h2 = __float22bfloat162_rn(make_float2(lo, hi));
    return u.s;
}
static __device__ __forceinline__ float bf2f(unsigned short s) {
    return __uint_as_float(((unsigned int)s) << 16);
}
static __device__ __forceinline__ v8s pk8(float4 a, float4 c) {
    union { v8s v; unsigned int u[4]; } r;
    r.u[0] = f2bf2(a.x, a.y);
    r.u[1] = f2bf2(a.z, a.w);
    r.u[2] = f2bf2(c.x, c.y);
    r.u[3] = f2bf2(c.z, c.w);
    return r.v;
}
static __device__ __forceinline__ v8s ld8bf(const float* __restrict__ p) {
    float4 a = *(const float4*)p;
    float4 c = *(const float4*)(p + 4);
    return pk8(a, c);
}

// ---------------- Single kernel, 256 blocks x 512 thr (8 waves, 2/SIMD) ----------------
// R7 changes vs R6 (latency/VALU path, all mechanism-independent):
//  - exp2f -> __builtin_amdgcn_exp2f (raw v_exp_f32; domain |e2|<~1, no libm fixup)
//  - a_out stores issued right after inv (post-barrier-2): 16MB drain overlaps
//    LN1+FFN+LN2 instead of being exposed at kernel end
//  - p2/p3 plane build uses packed v_cvt_pk_bf16_f32 (f2bf2) instead of 16 scalar cvts
// Barriers: (1) fq/c0s, (2) red+redB, (3) ysh, (4) h1sh, (5) h2. Five total.
// LDS map (58,432 B): klds/ash 0..32767 (aliased, wave-private lifetimes),
// red 32768..49151, fq 49152..52223 (3 planes), c0s 52224..52287,
// redB 52288..52799, ysh 52800..54079, h1sh 54080..58431.
__global__ __launch_bounds__(512) void fused_all(
    const float* __restrict__ x, const float* __restrict__ Wt,
    const float* __restrict__ Wx, const float* __restrict__ bh,
    const float* __restrict__ Wa,
    const float* __restrict__ gamma1, const float* __restrict__ beta1,
    const float* __restrict__ W1, const float* __restrict__ b1,
    const float* __restrict__ W2, const float* __restrict__ b2,
    const float* __restrict__ gamma2, const float* __restrict__ beta2,
    float* __restrict__ a_out, float* __restrict__ y2out)
{
    __shared__ __attribute__((aligned(16))) unsigned char smem[58432];
    unsigned short* klds = (unsigned short*)smem;            // 32KB (wave-private 4KB slices)
    unsigned short* ash  = (unsigned short*)smem;            // aliases klds (wave-private)
    float*          red  = (float*)(smem + 32768);           // 16KB
    unsigned short* fq   = (unsigned short*)(smem + 49152);  // 3 planes * 512 ush
    float*          c0s  = (float*)(smem + 52224);           // 16 f32
    float*          redB = (float*)(smem + 52288);           // 8*16 f32
    unsigned short* ysh  = (unsigned short*)(smem + 52800);  // 16*40 ush
    unsigned short* h1sh = (unsigned short*)(smem + 54080);  // 16*136 ush

    const int tid = threadIdx.x, lane = tid & 63, w = tid >> 6;   // w in [0,8)
    const int col = lane & 15, g = lane >> 4;
    const int bI = blockIdx.x;
    const int b = bI >> 6, t0 = (bI & 63) << 4;   // 16 rows per block
    const float* xb = x + (size_t)b * (NC * NT);

    // ---- phase A1: q features (deg-3, log2e folded), one (row,u) per thread;
    //      plane-0 row-sum reduced here into c0s (replaces the ones-MFMA) ----
    {
        int rl = tid >> 5, u = tid & 31;          // rl in [0,16), u in [0,32)
        const float* xp = xb + t0 + rl;
        float aq = 0.f;
        #pragma unroll
        for (int c = 0; c < NC; ++c) aq = fmaf(xp[c * NT], Wt[c * NU + u], aq);
        float q = aq + bh[u];
        float wa = Wa[u] * 1.4426950408889634f;   // fold log2(e): e*log2e -> exp2
        const float C1 = -0.33333334f;
        float q2 = q * q;
        float f0 = wa * fmaf(C1 * q, q2, q);      // plane 0 value (coeff of 1)
        unsigned short* fqp = fq + ((u >> 3) << 7) + (rl << 3) + (u & 7);
        fqp[0]    = f2bf(wa * fmaf(3.f * C1, q2, 1.f));    // plane: k
        fqp[512]  = f2bf(wa * (3.f * C1 * q));             // plane: k^2
        fqp[1024] = f2bf(wa * C1);                         // plane: k^3
        float c0 = f0;                             // sum over u (32 lanes, same rl)
        #pragma unroll
        for (int o = 1; o < 32; o <<= 1) c0 += __shfl_xor(c0, o);
        if (u == 0) c0s[rl] = c0;
    }

    // ---- phase A2: k-GEMV B-frags (Wx) ----
    v8s kb0, kb1;
    {
        int cc = g << 3;
        #pragma unroll
        for (int i = 0; i < 8; ++i) kb0[i] = (short)f2bf(Wx[(cc + i) * NU + col]);
        #pragma unroll
        for (int i = 0; i < 8; ++i) kb1[i] = (short)f2bf(Wx[(cc + i) * NU + 16 + col]);
    }

    // ---- phase A3: k-GEMV half 0 (tiles 0..3 of this wave) -> klds (wave-private) ----
    unsigned short* kw = klds + (w << 11);        // 2048 ush per wave
    #pragma unroll
    for (int tl = 0; tl < 4; ++tl) {
        int jt = (w << 3) + tl;
        int j = (jt << 4) + col;
        int c0i = g << 3;
        v8s ka;
        #pragma unroll
        for (int i = 0; i < 8; ++i) ka[i] = (short)f2bf(xb[(size_t)(c0i + i) * NT + j]);
        v4f d0 = {0.f, 0.f, 0.f, 0.f}, d1 = {0.f, 0.f, 0.f, 0.f};
        d0 = __builtin_amdgcn_mfma_f32_16x16x32_bf16(ka, kb0, d0, 0, 0, 0);
        d1 = __builtin_amdgcn_mfma_f32_16x16x32_bf16(ka, kb1, d1, 0, 0, 0);
        unsigned short* kt = kw + (tl << 9);
        #pragma unroll
        for (int r = 0; r < 4; ++r) {
            int jl = (g << 2) + r;
            kt[(((col >> 3) << 4) + jl) * 8 + (col & 7)]       = f2bf(d0[r]); // u=col
            kt[(((2 + (col >> 3)) << 4) + jl) * 8 + (col & 7)] = f2bf(d1[r]); // u=16+col
        }
    }
    __syncthreads();   // (1) fq + c0s ready (klds is wave-private)

    // ---- phase B: scores, K=96 over planes k,k^2,k^3 + scalar c0 init ----
    v8s afr[3];
    #pragma unroll
    for (int ks = 0; ks < 3; ++ks) afr[ks] = *(const v8s*)(fq + (ks << 9) + (lane << 3));
    float c0r[4];
    #pragma unroll
    for (int r = 0; r < 4; ++r) c0r[r] = c0s[(g << 2) + r];

    v4f acc[8];
    #pragma unroll
    for (int nt = 0; nt < 8; ++nt) acc[nt] = (v4f){c0r[0], c0r[1], c0r[2], c0r[3]};

    // scores half 0 (tiles 0..3, already staged)
    #pragma unroll
    for (int tl = 0; tl < 4; ++tl) {
        v8s k8 = *(const v8s*)(kw + (tl << 9) + (lane << 3));
        float kf[8], k2[8];
        #pragma unroll
        for (int i = 0; i < 8; ++i) { kf[i] = bf2f((unsigned short)k8[i]); k2[i] = kf[i] * kf[i]; }
        union { v8s v; unsigned int u[4]; } p2, p3;
        #pragma unroll
        for (int p = 0; p < 4; ++p) {
            p2.u[p] = f2bf2(k2[2*p], k2[2*p+1]);
            p3.u[p] = f2bf2(k2[2*p] * kf[2*p], k2[2*p+1] * kf[2*p+1]);
        }
        acc[tl] = __builtin_amdgcn_mfma_f32_16x16x32_bf16(afr[0], k8,   acc[tl], 0, 0, 0);
        acc[tl] = __builtin_amdgcn_mfma_f32_16x16x32_bf16(afr[1], p2.v, acc[tl], 0, 0, 0);
        acc[tl] = __builtin_amdgcn_mfma_f32_16x16x32_bf16(afr[2], p3.v, acc[tl], 0, 0, 0);
    }
    // k-GEMV half 1 (tiles 4..7) -> same klds slots (same-wave DS in-order)
    #pragma unroll
    for (int tl = 0; tl < 4; ++tl) {
        int jt = (w << 3) + 4 + tl;
        int j = (jt << 4) + col;
        int c0i = g << 3;
        v8s ka;
        #pragma unroll
        for (int i = 0; i < 8; ++i) ka[i] = (short)f2bf(xb[(size_t)(c0i + i) * NT + j]);
        v4f d0 = {0.f, 0.f, 0.f, 0.f}, d1 = {0.f, 0.f, 0.f, 0.f};
        d0 = __builtin_amdgcn_mfma_f32_16x16x32_bf16(ka, kb0, d0, 0, 0, 0);
        d1 = __builtin_amdgcn_mfma_f32_16x16x32_bf16(ka, kb1, d1, 0, 0, 0);
        unsigned short* kt = kw + (tl << 9);
        #pragma unroll
        for (int r = 0; r < 4; ++r) {
            int jl = (g << 2) + r;
            kt[(((col >> 3) << 4) + jl) * 8 + (col & 7)]       = f2bf(d0[r]);
            kt[(((2 + (col >> 3)) << 4) + jl) * 8 + (col & 7)] = f2bf(d1[r]);
        }
    }
    // scores half 1
    #pragma unroll
    for (int tl = 0; tl < 4; ++tl) {
        int nt = 4 + tl;
        v8s k8 = *(const v8s*)(kw + (tl << 9) + (lane << 3));
        float kf[8], k2[8];
        #pragma unroll
        for (int i = 0; i < 8; ++i) { kf[i] = bf2f((unsigned short)k8[i]); k2[i] = kf[i] * kf[i]; }
        union { v8s v; unsigned int u[4]; } p2, p3;
        #pragma unroll
        for (int p = 0; p < 4; ++p) {
            p2.u[p] = f2bf2(k2[2*p], k2[2*p+1]);
            p3.u[p] = f2bf2(k2[2*p] * kf[2*p], k2[2*p+1] * kf[2*p+1]);
        }
        acc[nt] = __builtin_amdgcn_mfma_f32_16x16x32_bf16(afr[0], k8,   acc[nt], 0, 0, 0);
        acc[nt] = __builtin_amdgcn_mfma_f32_16x16x32_bf16(afr[1], p2.v, acc[nt], 0, 0, 0);
        acc[nt] = __builtin_amdgcn_mfma_f32_16x16x32_bf16(afr[2], p3.v, acc[nt], 0, 0, 0);
    }

    // ---- prefetch phase-2 x fragments (issued before softmax VALU) ----
    float4 pf[4][4];
    #pragma unroll
    for (int i = 0; i < 4; ++i) {
        int it = (w << 2) + i;
        const float* xr0 = xb + (size_t)col * NT + (it << 5) + (g << 3);
        const float* xr1 = xb + (size_t)(col + 16) * NT + (it << 5) + (g << 3);
        pf[i][0] = *(const float4*)xr0; pf[i][1] = *(const float4*)(xr0 + 4);
        pf[i][2] = *(const float4*)xr1; pf[i][3] = *(const float4*)(xr1 + 4);
    }

    // ---- shift-free softmax numerator: e = exp2(e2) via raw v_exp_f32.
    //      |e2| <= ~1 so no overflow/denormal; max-shift cancels except through
    //      the +1e-5 denom term (~1e-9 relative -> negligible) ----
    float s4[4] = {0.f, 0.f, 0.f, 0.f};
    #pragma unroll
    for (int nt = 0; nt < 8; ++nt) {
        #pragma unroll
        for (int r = 0; r < 4; ++r) {
            float ev = __builtin_amdgcn_exp2f(acc[nt][r]);
            acc[nt][r] = ev;
            s4[r] += ev;
        }
    }
    #pragma unroll
    for (int r = 0; r < 4; ++r) {
        #pragma unroll
        for (int o = 1; o < 16; o <<= 1) s4[r] += __shfl_xor(s4[r], o);
    }
    if (col == 0) {
        #pragma unroll
        for (int r = 0; r < 4; ++r) redB[(w << 4) + (g << 2) + r] = s4[r];
    }

    // e (bf16, UNNORMALIZED) -> ash in A-fragment layout; wave-private, no barrier
    #pragma unroll
    for (int r = 0; r < 4; ++r) {
        int m = (g << 2) + r;
        #pragma unroll
        for (int nt = 0; nt < 8; ++nt) {
            int j = (w << 7) + (nt << 4) + col;
            ash[((j >> 5) << 9) + (((j >> 3) & 3) << 7) + (m << 3) + (j & 7)] = f2bf(acc[nt][r]);
        }
    }

    // ---- phase 2: v_unnorm = e@xt, K=1024 split 8 ways (wave w: it in [4w, 4w+4));
    //      ash reads are same-wave after own writes (DS in-order) ----
    v4f v0 = {0.f, 0.f, 0.f, 0.f}, v1 = {0.f, 0.f, 0.f, 0.f};
    #pragma unroll
    for (int i = 0; i < 4; ++i) {
        int it = (w << 2) + i;
        v8s af  = *(const v8s*)(ash + (it << 9) + (lane << 3));
        v8s bf0 = pk8(pf[i][0], pf[i][1]);
        v8s bf1 = pk8(pf[i][2], pf[i][3]);
        v0 = __builtin_amdgcn_mfma_f32_16x16x32_bf16(af, bf0, v0, 0, 0, 0);
        v1 = __builtin_amdgcn_mfma_f32_16x16x32_bf16(af, bf1, v1, 0, 0, 0);
    }
    #pragma unroll
    for (int r = 0; r < 4; ++r) {
        red[(((w << 3) + r) << 6) + lane]     = v0[r];
        red[(((w << 3) + 4 + r) << 6) + lane] = v1[r];
    }

    // ---- prefetch LN1 residual + FFN operands (before barrier 2) ----
    float xres0[4], xres1[4];
    #pragma unroll
    for (int r = 0; r < 4; ++r) {
        int t = t0 + (g << 2) + r;
        xres0[r] = xb[col * NT + t];
        xres1[r] = xb[(col + 16) * NT + t];
    }
    v8s w1f = ld8bf(W1 + ((w << 4) + col) * NC + (g << 3));
    float b1v = b1[(w << 4) + col];
    const int ct = w >> 2, kb2 = w & 3;
    v8s w2f = ld8bf(W2 + (col + (ct << 4)) * NH + (kb2 << 5) + (g << 3));
    float g1a = gamma1[col], be1a = beta1[col];
    float g1b = gamma1[col + 16], be1b = beta1[col + 16];
    float g2a = gamma2[col], be2a = beta2[col];
    float g2b = gamma2[col + 16], be2b = beta2[col + 16];
    float bb0 = b2[col], bb1 = b2[col + 16];
    __syncthreads();   // (2) red (v_unnorm) + redB (denoms) ready

    // ---- inv from redB (post-barrier; overlapped the v-GEMM) ----
    float inv[4];
    #pragma unroll
    for (int r = 0; r < 4; ++r) {
        float S = 0.f;
        #pragma unroll
        for (int w2 = 0; w2 < 8; ++w2) S += redB[(w2 << 4) + (g << 2) + r];
        inv[r] = 1.f / (S + 1e-5f);
    }

    // ---- a_out stores NOW (drain overlaps LN1+FFN+LN2): a = e * inv ----
    #pragma unroll
    for (int r = 0; r < 4; ++r) {
        int m = (g << 2) + r;
        size_t base = ((size_t)((bI << 4) + m) << 10) + (w << 7) + col;
        #pragma unroll
        for (int nt = 0; nt < 8; ++nt) {
            a_out[base + (nt << 4)] = acc[nt][r] * inv[r];
        }
    }

    // ---- LN1 (all waves redundantly; wave 0 stages y to LDS).
    //      v = inv[row] * sum(v_unnorm partials) ----
    float y0[4], y1[4];
    {
        float s0[4] = {0.f, 0.f, 0.f, 0.f}, s1[4] = {0.f, 0.f, 0.f, 0.f};
        #pragma unroll
        for (int w2 = 0; w2 < 8; ++w2) {
            #pragma unroll
            for (int r = 0; r < 4; ++r) {
                s0[r] += red[(((w2 << 3) + r) << 6) + lane];
                s1[r] += red[(((w2 << 3) + 4 + r) << 6) + lane];
            }
        }
        #pragma unroll
        for (int r = 0; r < 4; ++r) {
            float v0l = fmaf(s0[r], inv[r], xres0[r]);
            float v1l = fmaf(s1[r], inv[r], xres1[r]);
            float s = v0l + v1l, ss = v0l * v0l + v1l * v1l;
            #pragma unroll
            for (int msk = 1; msk < 16; msk <<= 1) {
                s  += __shfl_xor(s, msk);
                ss += __shfl_xor(ss, msk);
            }
            float mean = s * 0.03125f;
            float var = fmaf(-mean, mean, ss * 0.03125f) + 1e-14f;
            float rs = rsqrtf(var);
            y0[r] = (v0l - mean) * rs * g1a + be1a;
            y1[r] = (v1l - mean) * rs * g1b + be1b;
            if (w == 0) {
                int rowl = (g << 2) + r;
                ysh[rowl * 40 + col]      = f2bf(y0[r]);
                ysh[rowl * 40 + col + 16] = f2bf(y1[r]);
            }
        }
    }
    __syncthreads();   // (3) ysh ready

    // ---- h1 = relu(y @ W1^T + b1): wave w does n-tile w ----
    {
        v8s ya = *(const v8s*)(ysh + col * 40 + (g << 3));
        v4f hacc = {0.f, 0.f, 0.f, 0.f};
        hacc = __builtin_amdgcn_mfma_f32_16x16x32_bf16(ya, w1f, hacc, 0, 0, 0);
        #pragma unroll
        for (int r = 0; r < 4; ++r) {
            float hv = fmaxf(hacc[r] + b1v, 0.f);
            h1sh[((g << 2) + r) * 136 + (w << 4) + col] = f2bf(hv);
        }
    }
    __syncthreads();   // (4) h1sh ready

    // ---- h2 partial: wave w -> (ct, kb2) ----
    {
        v8s ha  = *(const v8s*)(h1sh + col * 136 + (kb2 << 5) + (g << 3));
        v4f hacc = {0.f, 0.f, 0.f, 0.f};
        hacc = __builtin_amdgcn_mfma_f32_16x16x32_bf16(ha, w2f, hacc, 0, 0, 0);
        #pragma unroll
        for (int r = 0; r < 4; ++r) red[(((w << 3) + r) << 6) + lane] = hacc[r];
    }
    __syncthreads();   // (5) h2 partials ready

    // ---- tail: y2 = LN2(y + ff), parallel across 8 waves (r = w&3, hf = w>>2) ----
    {
        int r = w & 3, hf = w >> 2;
        float ha0 = 0.f, ha1 = 0.f;
        #pragma unroll
        for (int w2 = 0; w2 < 4; ++w2) ha0 += red[(((w2 << 3) + r) << 6) + lane];
        #pragma unroll
        for (int w2 = 0; w2 < 4; ++w2) ha1 += red[((((w2 + 4) << 3) + r) << 6) + lane];
        float z0 = y0[r] + ha0 + bb0;
        float z1 = y1[r] + ha1 + bb1;
        float s = z0 + z1, ss = z0 * z0 + z1 * z1;
        #pragma unroll
        for (int msk = 1; msk < 16; msk <<= 1) {
            s  += __shfl_xor(s, msk);
            ss += __shfl_xor(ss, msk);
        }
        float mean = s * 0.03125f;
        float var = fmaf(-mean, mean, ss * 0.03125f) + 1e-14f;
        float rs = rsqrtf(var);
        int t = t0 + (g << 2) + r;
        float* yo = y2out + (size_t)b * (NC * NT);
        if (hf == 0) {
            yo[col * NT + t] = (z0 - mean) * rs * g2a + be2a;
        } else {
            yo[(col + 16) * NT + t] = (z1 - mean) * rs * g2b + be2b;
        }
    }
}

extern "C" void kernel_launch(void* const* d_in, const int* in_sizes, int n_in,
                              void* d_out, int out_size, void* d_ws, size_t ws_size,
                              hipStream_t stream)
{
    const float* x      = (const float*)d_in[0];
    const float* Wt     = (const float*)d_in[1];
    const float* Wx     = (const float*)d_in[2];
    const float* bh     = (const float*)d_in[3];
    const float* Wa     = (const float*)d_in[4];
    // d_in[5] = ba: cancels in softmax (shift-free: scales num & denom equally)
    const float* gamma1 = (const float*)d_in[6];
    const float* beta1  = (const float*)d_in[7];
    const float* W1     = (const float*)d_in[8];
    const float* b1     = (const float*)d_in[9];
    const float* W2     = (const float*)d_in[10];
    const float* b2     = (const float*)d_in[11];
    const float* gamma2 = (const float*)d_in[12];
    const float* beta2  = (const float*)d_in[13];

    float* out = (float*)d_out;
    float* y2o = out;            // B*C*T = 131072 f32
    float* a_o = out + 131072;   // B*T*T = 4194304 f32

    fused_all<<<256, 512, 0, stream>>>(x, Wt, Wx, bh, Wa,
                                       gamma1, beta1, W1, b1, W2, b2,
                                       gamma2, beta2, a_o, y2o);
}

// Round 8
// 95.086 us; speedup vs baseline: 1.0189x; 1.0189x over previous
//
#include <hip/hip_runtime.h>
#include <hip/hip_bf16.h>

typedef short v8s __attribute__((ext_vector_type(8)));
typedef float v4f __attribute__((ext_vector_type(4)));

#define NC 32
#define NT 1024
#define NU 32
#define NH 128

// Native RNE f32->bf16 (compiler lowers to v_cvt_pk_bf16_f32).
static __device__ __forceinline__ unsigned short f2bf(float f) {
    union { __hip_bfloat16 h; unsigned short s; } u;
    u.h = __float2bfloat16(f);
    return u.s;
}
static __device__ __forceinline__ unsigned int f2bf2(float lo, float hi) {
    union { __hip_bfloat162 h2; unsigned int s; } u;
    u.h2 = __float22bfloat162_rn(make_float2(lo, hi));
    return u.s;
}
static __device__ __forceinline__ float bf2f(unsigned short s) {
    return __uint_as_float(((unsigned int)s) << 16);
}
static __device__ __forceinline__ v8s pk8(float4 a, float4 c) {
    union { v8s v; unsigned int u[4]; } r;
    r.u[0] = f2bf2(a.x, a.y);
    r.u[1] = f2bf2(a.z, a.w);
    r.u[2] = f2bf2(c.x, c.y);
    r.u[3] = f2bf2(c.z, c.w);
    return r.v;
}
static __device__ __forceinline__ v8s ld8bf(const float* __restrict__ p) {
    float4 a = *(const float4*)p;
    float4 c = *(const float4*)(p + 4);
    return pk8(a, c);
}

// ---------------- Single kernel, 256 blocks x 512 thr (8 waves, 2/SIMD) ----------------
// R8 change vs R7: LN1 r-split — each wave computes LN1 only for r = w&3 (the one
// value its LN2 tail consumes); waves 0-3 stage ysh (rowl = g*4 + (w&3) covers all
// 16 rows). Removes 112 ds_read_b32 + 24 shuffles per thread from the redundant
// 4-r LN1. Arithmetic per retained value identical -> bit-identical outputs.
// Barriers: (1) fq/c0s, (2) red+redB, (3) ysh, (4) h1sh, (5) h2. Five total.
// LDS map (58,432 B): klds/ash 0..32767 (aliased, wave-private lifetimes),
// red 32768..49151, fq 49152..52223 (3 planes), c0s 52224..52287,
// redB 52288..52799, ysh 52800..54079, h1sh 54080..58431.
__global__ __launch_bounds__(512) void fused_all(
    const float* __restrict__ x, const float* __restrict__ Wt,
    const float* __restrict__ Wx, const float* __restrict__ bh,
    const float* __restrict__ Wa,
    const float* __restrict__ gamma1, const float* __restrict__ beta1,
    const float* __restrict__ W1, const float* __restrict__ b1,
    const float* __restrict__ W2, const float* __restrict__ b2,
    const float* __restrict__ gamma2, const float* __restrict__ beta2,
    float* __restrict__ a_out, float* __restrict__ y2out)
{
    __shared__ __attribute__((aligned(16))) unsigned char smem[58432];
    unsigned short* klds = (unsigned short*)smem;            // 32KB (wave-private 4KB slices)
    unsigned short* ash  = (unsigned short*)smem;            // aliases klds (wave-private)
    float*          red  = (float*)(smem + 32768);           // 16KB
    unsigned short* fq   = (unsigned short*)(smem + 49152);  // 3 planes * 512 ush
    float*          c0s  = (float*)(smem + 52224);           // 16 f32
    float*          redB = (float*)(smem + 52288);           // 8*16 f32
    unsigned short* ysh  = (unsigned short*)(smem + 52800);  // 16*40 ush
    unsigned short* h1sh = (unsigned short*)(smem + 54080);  // 16*136 ush

    const int tid = threadIdx.x, lane = tid & 63, w = tid >> 6;   // w in [0,8)
    const int col = lane & 15, g = lane >> 4;
    const int bI = blockIdx.x;
    const int b = bI >> 6, t0 = (bI & 63) << 4;   // 16 rows per block
    const float* xb = x + (size_t)b * (NC * NT);

    // ---- phase A1: q features (deg-3, log2e folded), one (row,u) per thread;
    //      plane-0 row-sum reduced here into c0s (replaces the ones-MFMA) ----
    {
        int rl = tid >> 5, u = tid & 31;          // rl in [0,16), u in [0,32)
        const float* xp = xb + t0 + rl;
        float aq = 0.f;
        #pragma unroll
        for (int c = 0; c < NC; ++c) aq = fmaf(xp[c * NT], Wt[c * NU + u], aq);
        float q = aq + bh[u];
        float wa = Wa[u] * 1.4426950408889634f;   // fold log2(e): e*log2e -> exp2
        const float C1 = -0.33333334f;
        float q2 = q * q;
        float f0 = wa * fmaf(C1 * q, q2, q);      // plane 0 value (coeff of 1)
        unsigned short* fqp = fq + ((u >> 3) << 7) + (rl << 3) + (u & 7);
        fqp[0]    = f2bf(wa * fmaf(3.f * C1, q2, 1.f));    // plane: k
        fqp[512]  = f2bf(wa * (3.f * C1 * q));             // plane: k^2
        fqp[1024] = f2bf(wa * C1);                         // plane: k^3
        float c0 = f0;                             // sum over u (32 lanes, same rl)
        #pragma unroll
        for (int o = 1; o < 32; o <<= 1) c0 += __shfl_xor(c0, o);
        if (u == 0) c0s[rl] = c0;
    }

    // ---- phase A2: k-GEMV B-frags (Wx) ----
    v8s kb0, kb1;
    {
        int cc = g << 3;
        #pragma unroll
        for (int i = 0; i < 8; ++i) kb0[i] = (short)f2bf(Wx[(cc + i) * NU + col]);
        #pragma unroll
        for (int i = 0; i < 8; ++i) kb1[i] = (short)f2bf(Wx[(cc + i) * NU + 16 + col]);
    }

    // ---- phase A3: k-GEMV half 0 (tiles 0..3 of this wave) -> klds (wave-private) ----
    unsigned short* kw = klds + (w << 11);        // 2048 ush per wave
    #pragma unroll
    for (int tl = 0; tl < 4; ++tl) {
        int jt = (w << 3) + tl;
        int j = (jt << 4) + col;
        int c0i = g << 3;
        v8s ka;
        #pragma unroll
        for (int i = 0; i < 8; ++i) ka[i] = (short)f2bf(xb[(size_t)(c0i + i) * NT + j]);
        v4f d0 = {0.f, 0.f, 0.f, 0.f}, d1 = {0.f, 0.f, 0.f, 0.f};
        d0 = __builtin_amdgcn_mfma_f32_16x16x32_bf16(ka, kb0, d0, 0, 0, 0);
        d1 = __builtin_amdgcn_mfma_f32_16x16x32_bf16(ka, kb1, d1, 0, 0, 0);
        unsigned short* kt = kw + (tl << 9);
        #pragma unroll
        for (int r = 0; r < 4; ++r) {
            int jl = (g << 2) + r;
            kt[(((col >> 3) << 4) + jl) * 8 + (col & 7)]       = f2bf(d0[r]); // u=col
            kt[(((2 + (col >> 3)) << 4) + jl) * 8 + (col & 7)] = f2bf(d1[r]); // u=16+col
        }
    }
    __syncthreads();   // (1) fq + c0s ready (klds is wave-private)

    // ---- phase B: scores, K=96 over planes k,k^2,k^3 + scalar c0 init ----
    v8s afr[3];
    #pragma unroll
    for (int ks = 0; ks < 3; ++ks) afr[ks] = *(const v8s*)(fq + (ks << 9) + (lane << 3));
    float c0r[4];
    #pragma unroll
    for (int r = 0; r < 4; ++r) c0r[r] = c0s[(g << 2) + r];

    v4f acc[8];
    #pragma unroll
    for (int nt = 0; nt < 8; ++nt) acc[nt] = (v4f){c0r[0], c0r[1], c0r[2], c0r[3]};

    // scores half 0 (tiles 0..3, already staged)
    #pragma unroll
    for (int tl = 0; tl < 4; ++tl) {
        v8s k8 = *(const v8s*)(kw + (tl << 9) + (lane << 3));
        float kf[8], k2[8];
        #pragma unroll
        for (int i = 0; i < 8; ++i) { kf[i] = bf2f((unsigned short)k8[i]); k2[i] = kf[i] * kf[i]; }
        union { v8s v; unsigned int u[4]; } p2, p3;
        #pragma unroll
        for (int p = 0; p < 4; ++p) {
            p2.u[p] = f2bf2(k2[2*p], k2[2*p+1]);
            p3.u[p] = f2bf2(k2[2*p] * kf[2*p], k2[2*p+1] * kf[2*p+1]);
        }
        acc[tl] = __builtin_amdgcn_mfma_f32_16x16x32_bf16(afr[0], k8,   acc[tl], 0, 0, 0);
        acc[tl] = __builtin_amdgcn_mfma_f32_16x16x32_bf16(afr[1], p2.v, acc[tl], 0, 0, 0);
        acc[tl] = __builtin_amdgcn_mfma_f32_16x16x32_bf16(afr[2], p3.v, acc[tl], 0, 0, 0);
    }
    // k-GEMV half 1 (tiles 4..7) -> same klds slots (same-wave DS in-order)
    #pragma unroll
    for (int tl = 0; tl < 4; ++tl) {
        int jt = (w << 3) + 4 + tl;
        int j = (jt << 4) + col;
        int c0i = g << 3;
        v8s ka;
        #pragma unroll
        for (int i = 0; i < 8; ++i) ka[i] = (short)f2bf(xb[(size_t)(c0i + i) * NT + j]);
        v4f d0 = {0.f, 0.f, 0.f, 0.f}, d1 = {0.f, 0.f, 0.f, 0.f};
        d0 = __builtin_amdgcn_mfma_f32_16x16x32_bf16(ka, kb0, d0, 0, 0, 0);
        d1 = __builtin_amdgcn_mfma_f32_16x16x32_bf16(ka, kb1, d1, 0, 0, 0);
        unsigned short* kt = kw + (tl << 9);
        #pragma unroll
        for (int r = 0; r < 4; ++r) {
            int jl = (g << 2) + r;
            kt[(((col >> 3) << 4) + jl) * 8 + (col & 7)]       = f2bf(d0[r]);
            kt[(((2 + (col >> 3)) << 4) + jl) * 8 + (col & 7)] = f2bf(d1[r]);
        }
    }
    // scores half 1
    #pragma unroll
    for (int tl = 0; tl < 4; ++tl) {
        int nt = 4 + tl;
        v8s k8 = *(const v8s*)(kw + (tl << 9) + (lane << 3));
        float kf[8], k2[8];
        #pragma unroll
        for (int i = 0; i < 8; ++i) { kf[i] = bf2f((unsigned short)k8[i]); k2[i] = kf[i] * kf[i]; }
        union { v8s v; unsigned int u[4]; } p2, p3;
        #pragma unroll
        for (int p = 0; p < 4; ++p) {
            p2.u[p] = f2bf2(k2[2*p], k2[2*p+1]);
            p3.u[p] = f2bf2(k2[2*p] * kf[2*p], k2[2*p+1] * kf[2*p+1]);
        }
        acc[nt] = __builtin_amdgcn_mfma_f32_16x16x32_bf16(afr[0], k8,   acc[nt], 0, 0, 0);
        acc[nt] = __builtin_amdgcn_mfma_f32_16x16x32_bf16(afr[1], p2.v, acc[nt], 0, 0, 0);
        acc[nt] = __builtin_amdgcn_mfma_f32_16x16x32_bf16(afr[2], p3.v, acc[nt], 0, 0, 0);
    }

    // ---- prefetch phase-2 x fragments (issued before softmax VALU) ----
    float4 pf[4][4];
    #pragma unroll
    for (int i = 0; i < 4; ++i) {
        int it = (w << 2) + i;
        const float* xr0 = xb + (size_t)col * NT + (it << 5) + (g << 3);
        const float* xr1 = xb + (size_t)(col + 16) * NT + (it << 5) + (g << 3);
        pf[i][0] = *(const float4*)xr0; pf[i][1] = *(const float4*)(xr0 + 4);
        pf[i][2] = *(const float4*)xr1; pf[i][3] = *(const float4*)(xr1 + 4);
    }

    // ---- shift-free softmax numerator: e = exp2(e2) via raw v_exp_f32.
    //      |e2| <= ~1 so no overflow/denormal; max-shift cancels except through
    //      the +1e-5 denom term (~1e-9 relative -> negligible) ----
    float s4[4] = {0.f, 0.f, 0.f, 0.f};
    #pragma unroll
    for (int nt = 0; nt < 8; ++nt) {
        #pragma unroll
        for (int r = 0; r < 4; ++r) {
            float ev = __builtin_amdgcn_exp2f(acc[nt][r]);
            acc[nt][r] = ev;
            s4[r] += ev;
        }
    }
    #pragma unroll
    for (int r = 0; r < 4; ++r) {
        #pragma unroll
        for (int o = 1; o < 16; o <<= 1) s4[r] += __shfl_xor(s4[r], o);
    }
    if (col == 0) {
        #pragma unroll
        for (int r = 0; r < 4; ++r) redB[(w << 4) + (g << 2) + r] = s4[r];
    }

    // e (bf16, UNNORMALIZED) -> ash in A-fragment layout; wave-private, no barrier
    #pragma unroll
    for (int r = 0; r < 4; ++r) {
        int m = (g << 2) + r;
        #pragma unroll
        for (int nt = 0; nt < 8; ++nt) {
            int j = (w << 7) + (nt << 4) + col;
            ash[((j >> 5) << 9) + (((j >> 3) & 3) << 7) + (m << 3) + (j & 7)] = f2bf(acc[nt][r]);
        }
    }

    // ---- phase 2: v_unnorm = e@xt, K=1024 split 8 ways (wave w: it in [4w, 4w+4));
    //      ash reads are same-wave after own writes (DS in-order) ----
    v4f v0 = {0.f, 0.f, 0.f, 0.f}, v1 = {0.f, 0.f, 0.f, 0.f};
    #pragma unroll
    for (int i = 0; i < 4; ++i) {
        int it = (w << 2) + i;
        v8s af  = *(const v8s*)(ash + (it << 9) + (lane << 3));
        v8s bf0 = pk8(pf[i][0], pf[i][1]);
        v8s bf1 = pk8(pf[i][2], pf[i][3]);
        v0 = __builtin_amdgcn_mfma_f32_16x16x32_bf16(af, bf0, v0, 0, 0, 0);
        v1 = __builtin_amdgcn_mfma_f32_16x16x32_bf16(af, bf1, v1, 0, 0, 0);
    }
    #pragma unroll
    for (int r = 0; r < 4; ++r) {
        red[(((w << 3) + r) << 6) + lane]     = v0[r];
        red[(((w << 3) + 4 + r) << 6) + lane] = v1[r];
    }

    // ---- prefetch LN1 residual (only r = w&3 needed) + FFN operands ----
    const int rr = w & 3;
    float xres0, xres1;
    {
        int t = t0 + (g << 2) + rr;
        xres0 = xb[col * NT + t];
        xres1 = xb[(col + 16) * NT + t];
    }
    v8s w1f = ld8bf(W1 + ((w << 4) + col) * NC + (g << 3));
    float b1v = b1[(w << 4) + col];
    const int ct = w >> 2, kb2 = w & 3;
    v8s w2f = ld8bf(W2 + (col + (ct << 4)) * NH + (kb2 << 5) + (g << 3));
    float g1a = gamma1[col], be1a = beta1[col];
    float g1b = gamma1[col + 16], be1b = beta1[col + 16];
    float g2a = gamma2[col], be2a = beta2[col];
    float g2b = gamma2[col + 16], be2b = beta2[col + 16];
    float bb0 = b2[col], bb1 = b2[col + 16];
    __syncthreads();   // (2) red (v_unnorm) + redB (denoms) ready

    // ---- inv from redB (post-barrier; overlapped the v-GEMM) ----
    float inv[4];
    #pragma unroll
    for (int r = 0; r < 4; ++r) {
        float S = 0.f;
        #pragma unroll
        for (int w2 = 0; w2 < 8; ++w2) S += redB[(w2 << 4) + (g << 2) + r];
        inv[r] = 1.f / (S + 1e-5f);
    }

    // ---- a_out stores NOW (drain overlaps LN1+FFN+LN2): a = e * inv ----
    #pragma unroll
    for (int r = 0; r < 4; ++r) {
        int m = (g << 2) + r;
        size_t base = ((size_t)((bI << 4) + m) << 10) + (w << 7) + col;
        #pragma unroll
        for (int nt = 0; nt < 8; ++nt) {
            a_out[base + (nt << 4)] = acc[nt][r] * inv[r];
        }
    }

    // ---- LN1, r-split: wave w computes only r = rr = w&3; waves 0-3 stage ysh
    //      (rowl = g*4 + rr covers all 16 rows across waves 0-3) ----
    float y0r, y1r;
    {
        float s0 = 0.f, s1 = 0.f;
        #pragma unroll
        for (int w2 = 0; w2 < 8; ++w2) {
            s0 += red[(((w2 << 3) + rr) << 6) + lane];
            s1 += red[(((w2 << 3) + 4 + rr) << 6) + lane];
        }
        float v0l = fmaf(s0, inv[rr], xres0);
        float v1l = fmaf(s1, inv[rr], xres1);
        float s = v0l + v1l, ss = v0l * v0l + v1l * v1l;
        #pragma unroll
        for (int msk = 1; msk < 16; msk <<= 1) {
            s  += __shfl_xor(s, msk);
            ss += __shfl_xor(ss, msk);
        }
        float mean = s * 0.03125f;
        float var = fmaf(-mean, mean, ss * 0.03125f) + 1e-14f;
        float rs = rsqrtf(var);
        y0r = (v0l - mean) * rs * g1a + be1a;
        y1r = (v1l - mean) * rs * g1b + be1b;
        if (w < 4) {
            int rowl = (g << 2) + rr;
            ysh[rowl * 40 + col]      = f2bf(y0r);
            ysh[rowl * 40 + col + 16] = f2bf(y1r);
        }
    }
    __syncthreads();   // (3) ysh ready

    // ---- h1 = relu(y @ W1^T + b1): wave w does n-tile w ----
    {
        v8s ya = *(const v8s*)(ysh + col * 40 + (g << 3));
        v4f hacc = {0.f, 0.f, 0.f, 0.f};
        hacc = __builtin_amdgcn_mfma_f32_16x16x32_bf16(ya, w1f, hacc, 0, 0, 0);
        #pragma unroll
        for (int r = 0; r < 4; ++r) {
            float hv = fmaxf(hacc[r] + b1v, 0.f);
            h1sh[((g << 2) + r) * 136 + (w << 4) + col] = f2bf(hv);
        }
    }
    __syncthreads();   // (4) h1sh ready

    // ---- h2 partial: wave w -> (ct, kb2) ----
    {
        v8s ha  = *(const v8s*)(h1sh + col * 136 + (kb2 << 5) + (g << 3));
        v4f hacc = {0.f, 0.f, 0.f, 0.f};
        hacc = __builtin_amdgcn_mfma_f32_16x16x32_bf16(ha, w2f, hacc, 0, 0, 0);
        #pragma unroll
        for (int r = 0; r < 4; ++r) red[(((w << 3) + r) << 6) + lane] = hacc[r];
    }
    __syncthreads();   // (5) h2 partials ready

    // ---- tail: y2 = LN2(y + ff), parallel across 8 waves (r = rr, hf = w>>2) ----
    {
        int hf = w >> 2;
        float ha0 = 0.f, ha1 = 0.f;
        #pragma unroll
        for (int w2 = 0; w2 < 4; ++w2) ha0 += red[(((w2 << 3) + rr) << 6) + lane];
        #pragma unroll
        for (int w2 = 0; w2 < 4; ++w2) ha1 += red[((((w2 + 4) << 3) + rr) << 6) + lane];
        float z0 = y0r + ha0 + bb0;
        float z1 = y1r + ha1 + bb1;
        float s = z0 + z1, ss = z0 * z0 + z1 * z1;
        #pragma unroll
        for (int msk = 1; msk < 16; msk <<= 1) {
            s  += __shfl_xor(s, msk);
            ss += __shfl_xor(ss, msk);
        }
        float mean = s * 0.03125f;
        float var = fmaf(-mean, mean, ss * 0.03125f) + 1e-14f;
        float rs = rsqrtf(var);
        int t = t0 + (g << 2) + rr;
        float* yo = y2out + (size_t)b * (NC * NT);
        if (hf == 0) {
            yo[col * NT + t] = (z0 - mean) * rs * g2a + be2a;
        } else {
            yo[(col + 16) * NT + t] = (z1 - mean) * rs * g2b + be2b;
        }
    }
}

extern "C" void kernel_launch(void* const* d_in, const int* in_sizes, int n_in,
                              void* d_out, int out_size, void* d_ws, size_t ws_size,
                              hipStream_t stream)
{
    const float* x      = (const float*)d_in[0];
    const float* Wt     = (const float*)d_in[1];
    const float* Wx     = (const float*)d_in[2];
    const float* bh     = (const float*)d_in[3];
    const float* Wa     = (const float*)d_in[4];
    // d_in[5] = ba: cancels in softmax (shift-free: scales num & denom equally)
    const float* gamma1 = (const float*)d_in[6];
    const float* beta1  = (const float*)d_in[7];
    const float* W1     = (const float*)d_in[8];
    const float* b1     = (const float*)d_in[9];
    const float* W2     = (const float*)d_in[10];
    const float* b2     = (const float*)d_in[11];
    const float* gamma2 = (const float*)d_in[12];
    const float* beta2  = (const float*)d_in[13];

    float* out = (float*)d_out;
    float* y2o = out;            // B*C*T = 131072 f32
    float* a_o = out + 131072;   // B*T*T = 4194304 f32

    fused_all<<<256, 512, 0, stream>>>(x, Wt, Wx, bh, Wa,
                                       gamma1, beta1, W1, b1, W2, b2,
                                       gamma2, beta2, a_o, y2o);
}